// Round 5
// baseline (108.994 us; speedup 1.0000x reference)
//
#include <hip/hip_runtime.h>
#include <stdint.h>

#define IN_F   4096
#define OUT_F  768
#define NB     8
#define BATCH  4096
#define WCOLS  (OUT_F*NB)   // 6144

typedef short  bf16x8  __attribute__((ext_vector_type(8)));
typedef float  f32x4   __attribute__((ext_vector_type(4)));
typedef unsigned short ushort8 __attribute__((ext_vector_type(8)));

__device__ __forceinline__ unsigned short f2bf(float f){
    union { float f; uint32_t u; } v; v.f = f;
    uint32_t u = v.u;
    u += 0x7FFFu + ((u >> 16) & 1u);   // round-to-nearest-even
    return (unsigned short)(u >> 16);
}

__device__ __forceinline__ float bf2f(unsigned short u){
    union { uint32_t q; float f; } v; v.q = ((uint32_t)u) << 16;
    return v.f;
}

__device__ __forceinline__ void gload16(const void* g, void* l){
    __builtin_amdgcn_global_load_lds(
        (const __attribute__((address_space(1))) unsigned int*)g,
        (__attribute__((address_space(3))) unsigned int*)l, 16, 0, 0);
}

// counted vmcnt wait + scheduler fence (rule #18)
#define WAITV(n) do {                                                   \
    asm volatile("s_waitcnt vmcnt(" #n ")" ::: "memory");               \
    __builtin_amdgcn_sched_barrier(0);                                  \
} while (0)

// ---------------- kernel 1: latent f32 -> bf16 ; zero accumulators ----------
__global__ void prep_latent(const float* __restrict__ lat,
                            unsigned short* __restrict__ abf,
                            float* __restrict__ acc){
    if (blockIdx.x == 0 && threadIdx.x < 4) acc[threadIdx.x] = 0.f;
    int idx = (blockIdx.x * 256 + threadIdx.x) * 8;   // 8 floats / thread
    const float4* p = (const float4*)(lat + idx);
    float4 a = p[0], b = p[1];
    ushort8 o;
    o[0]=f2bf(a.x); o[1]=f2bf(a.y); o[2]=f2bf(a.z); o[3]=f2bf(a.w);
    o[4]=f2bf(b.x); o[5]=f2bf(b.y); o[6]=f2bf(b.z); o[7]=f2bf(b.w);
    *(ushort8*)(abf + idx) = o;
}

// ---------------- kernel 2: sigmoid-decode weight -> int_weights^T (bf16) ---
__global__ void decode_weight(const float* __restrict__ w,
                              unsigned short* __restrict__ bt,
                              float* __restrict__ acc){
    __shared__ unsigned short tile[64][70];   // [n][k], padded stride
    __shared__ float part[4];
    const int tid = threadIdx.x;
    const int k0 = blockIdx.x * 64;
    const int n0 = blockIdx.y * 64;
    const int j     = tid & 63;        // n within tile
    const int ibase = (tid >> 6) * 16; // k within tile
    float pol = 0.f;
    #pragma unroll 4
    for (int r = 0; r < 16; ++r){
        int i = ibase + r;
        const float4* src = (const float4*)(w + (size_t)(k0+i)*WCOLS + (size_t)(n0+j)*8);
        float4 a = src[0], b = src[1];
        float x[8] = {a.x,a.y,a.z,a.w,b.x,b.y,b.z,b.w};
        float p[8];
        #pragma unroll
        for (int q = 0; q < 8; ++q){
            p[q] = 1.f / (1.f + __expf(-x[q]));
            pol += p[q] * (1.f - p[q]);
        }
        float iw = p[0] + 2.f*p[1] + 4.f*p[2] + 8.f*p[3]
                 + 16.f*p[4] + 32.f*p[5] + 64.f*p[6] - 128.f*p[7];
        tile[j][i] = f2bf(iw);
    }
    #pragma unroll
    for (int off = 32; off; off >>= 1) pol += __shfl_down(pol, off);
    if ((tid & 63) == 0) part[tid >> 6] = pol;
    __syncthreads();
    const int nrow = tid >> 4;
    const int kb   = (tid & 15) * 4;
    #pragma unroll
    for (int q = 0; q < 4; ++q){
        int n = nrow + q*16;
        uint2 v;
        v.x = *(const unsigned int*)&tile[n][kb];
        v.y = *(const unsigned int*)&tile[n][kb+2];
        *(uint2*)(bt + (size_t)(n0+n)*IN_F + k0 + kb) = v;
    }
    if (tid == 0) atomicAdd(&acc[1], part[0]+part[1]+part[2]+part[3]);
}

// ---------------- kernel 2b: true_sum bits -> isum (bf16, [BATCH][OUT_F]) ---
__global__ void ts_decode(const float* __restrict__ ts,
                          unsigned short* __restrict__ isum){
    const int tid = threadIdx.x;
    #pragma unroll
    for (int k = 0; k < 6; ++k){
        int e = blockIdx.x * 1536 + k * 256 + tid;
        const float4* q = (const float4*)(ts + (size_t)e * 8);
        float4 x = q[0], y = q[1];
        float v = x.x + 2.f*x.y + 4.f*x.z + 8.f*x.w
                + 16.f*y.x + 32.f*y.y + 64.f*y.z - 128.f*y.w;
        isum[e] = f2bf(v);
    }
}

// ---------------- kernel 3: bf16 GEMM, producer/consumer wave split ---------
#define BM 64
#define BN 96
#define BK 64
#define NT (IN_F/BK)            // 64 K-steps
#define ABYTES (BM*BK*2)        // 8192
#define BBYTES (BN*BK*2)        // 12288
#define BUFB   (ABYTES+BBYTES)  // 20480

__launch_bounds__(512, 4)
__global__ void gemm_loss(const unsigned short* __restrict__ abf,
                          const unsigned short* __restrict__ bt,
                          const unsigned short* __restrict__ isum,
                          float* __restrict__ acc){
    __shared__ char smem[3*BUFB];   // 60 KB -> 2 blocks/CU
    __shared__ float part[8];
    const int tid = threadIdx.x;
    const int w   = tid >> 6;
    const int l   = tid & 63;
    const int s   = l & 15, g = l >> 4;
    const int wr  = w >> 1, wc = w & 1;    // consumers: 2x2, wave tile 32x48
    const int bid = blockIdx.x;
    const int m0  = (bid >> 3) * BM;       // XCD-aware: bid&7 = n-panel,
    const int n0  = (bid & 7)  * BN;       // so each XCD keeps one B panel hot

    f32x4 accv[2][3];
    #pragma unroll
    for (int m = 0; m < 2; ++m)
        #pragma unroll
        for (int n = 0; n < 3; ++n)
            accv[m][n] = (f32x4){0.f,0.f,0.f,0.f};

    #define COMPUTE(base) do {                                             \
        char* _Ab = (base);                                                \
        char* _Bb = (base) + ABYTES;                                       \
        _Pragma("unroll")                                                  \
        for (int _kk = 0; _kk < 2; ++_kk){                                 \
            bf16x8 _af[2], _bf[3];                                         \
            _Pragma("unroll")                                              \
            for (int _m = 0; _m < 2; ++_m){                                \
                int _r  = wr*32 + _m*16 + s;                               \
                int _ch = _r*8 + ((_kk*4 + g) ^ (_r & 7));                 \
                _af[_m] = *(const bf16x8*)(_Ab + _ch*16);                  \
            }                                                              \
            _Pragma("unroll")                                              \
            for (int _n = 0; _n < 3; ++_n){                                \
                int _r  = wc*48 + _n*16 + s;                               \
                int _ch = _r*8 + ((_kk*4 + g) ^ (_r & 7));                 \
                _bf[_n] = *(const bf16x8*)(_Bb + _ch*16);                  \
            }                                                              \
            __builtin_amdgcn_s_setprio(1);                                 \
            _Pragma("unroll")                                              \
            for (int _m = 0; _m < 2; ++_m)                                 \
                _Pragma("unroll")                                          \
                for (int _n = 0; _n < 3; ++_n)                             \
                    accv[_m][_n] = __builtin_amdgcn_mfma_f32_16x16x32_bf16(\
                        _af[_m], _bf[_n], accv[_m][_n], 0, 0, 0);          \
            __builtin_amdgcn_s_setprio(0);                                 \
        }                                                                  \
    } while (0)

    char* r0 = smem;             // tile t
    char* r1 = smem + BUFB;      // tile t+1
    char* r2 = smem + 2*BUFB;    // tile t+2 (stage target)

    if (w >= 4){
        // ---------- producer waves: 5 chunk-loads (1 KB each) per tile ------
        const int p  = w - 4;           // 0..3
        const int lr = l >> 3;          // row within 8-row chunk
        const int lc = l & 7;           // 16B column
        const unsigned short* src[5];
        int dsto[5];
        #pragma unroll
        for (int i = 0; i < 5; ++i){
            int c   = p + 4*i;          // chunk 0..19 (A:0-7, B:8-19)
            int row = (c < 8) ? (c*8 + lr) : ((c-8)*8 + lr);
            int csw = ((lc ^ (row & 7)) << 3);   // XOR-swizzled source col
            src[i]  = (c < 8) ? (abf + (size_t)(m0 + row)*IN_F + csw)
                              : (bt  + (size_t)(n0 + row)*IN_F + csw);
            dsto[i] = c * 1024;         // linear LDS chunk (wave-uniform base)
        }
        #define STAGEP(kt, base) do {                                     \
            _Pragma("unroll")                                             \
            for (int _i = 0; _i < 5; ++_i)                                \
                gload16(src[_i] + (size_t)(kt)*BK, (base) + dsto[_i]);    \
        } while (0)

        STAGEP(0, r0);
        STAGEP(1, r1);
        WAITV(5);                          // tile 0 landed
        __builtin_amdgcn_s_barrier();      // publish tile 0
        for (int t = 0; t < NT; ++t){
            __builtin_amdgcn_sched_barrier(0);
            if (t < NT-2)      { STAGEP(t+2, r2); WAITV(5); }  // t+1 landed
            else if (t == NT-2){ WAITV(0); }                   // last tile in
            __builtin_amdgcn_s_barrier();  // publish tile t+1; consumers done t
            char* tmp = r0; r0 = r1; r1 = r2; r2 = tmp;
        }
    } else {
        // ---------- consumer waves: pure ds_read + MFMA ---------------------
        __builtin_amdgcn_s_barrier();      // tile 0 ready
        for (int t = 0; t < NT; ++t){
            __builtin_amdgcn_sched_barrier(0);
            COMPUTE(r0);
            __builtin_amdgcn_sched_barrier(0);
            __builtin_amdgcn_s_barrier();
            char* tmp = r0; r0 = r1; r1 = r2; r2 = tmp;
        }
    }

    // epilogue: pred - isum (bf16 precomputed), accumulate squared error
    float local = 0.f;
    if (w < 4){
        #pragma unroll
        for (int m = 0; m < 2; ++m){
            int rbase = m0 + wr*32 + m*16 + g*4;
            #pragma unroll
            for (int n = 0; n < 3; ++n){
                int col = n0 + wc*48 + n*16 + s;
                #pragma unroll
                for (int jj = 0; jj < 4; ++jj){
                    float is = bf2f(isum[(size_t)(rbase+jj)*OUT_F + col]);
                    float d = accv[m][n][jj] - is;
                    local += d*d;
                }
            }
        }
    }
    #pragma unroll
    for (int off = 32; off; off >>= 1) local += __shfl_down(local, off);
    if (l == 0) part[w] = local;
    __syncthreads();
    if (tid == 0){
        float ssum = 0.f;
        #pragma unroll
        for (int i = 0; i < 8; ++i) ssum += part[i];
        atomicAdd(&acc[0], ssum);
    }
}

// ---------------- kernel 4: finalize ----------------------------------------
__global__ void finalize(const float* __restrict__ acc, float* __restrict__ out){
    out[0] = acc[0] * (1.0f / ((float)BATCH * (float)OUT_F * 128.0f));
    out[1] = acc[1] * (1.0f / ((float)IN_F * (float)WCOLS));
}

extern "C" void kernel_launch(void* const* d_in, const int* in_sizes, int n_in,
                              void* d_out, int out_size, void* d_ws, size_t ws_size,
                              hipStream_t stream){
    const float* latent   = (const float*)d_in[0];
    const float* true_sum = (const float*)d_in[1];
    const float* weight   = (const float*)d_in[2];
    float* acc = (float*)d_ws;
    unsigned short* abf  = (unsigned short*)((char*)d_ws + 1024);
    unsigned short* bt   = (unsigned short*)((char*)d_ws + 1024 + (size_t)BATCH*IN_F*2);
    unsigned short* isum = (unsigned short*)((char*)d_ws + 1024 + (size_t)BATCH*IN_F*2
                                             + (size_t)OUT_F*IN_F*2);
    float* out = (float*)d_out;

    prep_latent<<<(BATCH*IN_F)/(256*8), 256, 0, stream>>>(latent, abf, acc);
    decode_weight<<<dim3(IN_F/64, OUT_F/64), 256, 0, stream>>>(weight, bt, acc);
    ts_decode<<<(BATCH*OUT_F)/(256*6), 256, 0, stream>>>(true_sum, isum);
    gemm_loss<<<BATCH/BM * OUT_F/BN, 512, 0, stream>>>(abf, bt, isum, acc);
    finalize<<<1, 1, 0, stream>>>(acc, out);
}